// Round 1
// 1413.002 us; speedup vs baseline: 1.1286x; 1.1286x over previous
//
#include <hip/hip_runtime.h>
#include <math.h>

#define NN 6144
#define NH 256

__device__ __forceinline__ float4 ld4(const float* p) { return *(const float4*)p; }
__device__ __forceinline__ void st4(float* p, float4 v) { *(float4*)p = v; }

__device__ __forceinline__ float4 blend4(float4 x0, float4 x1, float4 x2,
                                         float4 n0, float4 n1, float4 n2) {
    float4 r;
    r.x = x0.x*n0.x + x1.x*n1.x + x2.x*n2.x;
    r.y = x0.y*n0.y + x1.y*n1.y + x2.y*n2.y;
    r.z = x0.z*n0.z + x1.z*n1.z + x2.z*n2.z;
    r.w = x0.w*n0.w + x1.w*n1.w + x2.w*n2.w;
    return r;
}

// ---------------- K1: gating -> nzT [3][6144] and nj output ----------------
__global__ __launch_bounds__(256) void gating_kernel(
    const float* __restrict__ adj0, const float* __restrict__ adj1, const float* __restrict__ adj2,
    const float* __restrict__ W1, const float* __restrict__ b1,
    const float* __restrict__ W2, const float* __restrict__ b2,
    const float* __restrict__ W3, const float* __restrict__ b3,
    const float* __restrict__ Wagg, const float* __restrict__ bagg,
    float* __restrict__ nzT, float* __restrict__ nj_out)
{
    const int i = blockIdx.x;
    const int t = threadIdx.x;
    __shared__ float w1s[1280], w2s[1280], w3s[1280];
    __shared__ float red[4][15];
    __shared__ float bc[3];
    float acc[15];
#pragma unroll
    for (int q = 0; q < 15; ++q) acc[q] = 0.f;
    const float* a0r = adj0 + (size_t)i * NN;
    const float* a1r = adj1 + (size_t)i * NN;
    const float* a2r = adj2 + (size_t)i * NN;
    for (int ch = 0; ch < 24; ++ch) {
        const int base = ch * 1280;
        __syncthreads();
#pragma unroll
        for (int q = 0; q < 5; ++q) {
            w1s[t + q*256] = W1[base + t + q*256];
            w2s[t + q*256] = W2[base + t + q*256];
            w3s[t + q*256] = W3[base + t + q*256];
        }
        __syncthreads();
        const int j = ch*256 + t;
        const float a0 = a0r[j], a1 = a1r[j], a2 = a2r[j];
#pragma unroll
        for (int q = 0; q < 5; ++q) {
            acc[q]    += a0 * w1s[t*5+q];
            acc[5+q]  += a1 * w2s[t*5+q];
            acc[10+q] += a2 * w3s[t*5+q];
        }
    }
#pragma unroll
    for (int q = 0; q < 15; ++q) {
        float v = acc[q];
        for (int d = 1; d < 64; d <<= 1) v += __shfl_xor(v, d, 64);
        acc[q] = v;
    }
    const int wave = t >> 6;
    if ((t & 63) == 0) {
#pragma unroll
        for (int q = 0; q < 15; ++q) red[wave][q] = acc[q];
    }
    __syncthreads();
    if (t == 0) {
        float cat[15];
#pragma unroll
        for (int q = 0; q < 15; ++q)
            cat[q] = red[0][q] + red[1][q] + red[2][q] + red[3][q];
#pragma unroll
        for (int q = 0; q < 5; ++q) { cat[q] += b1[q]; cat[5+q] += b2[q]; cat[10+q] += b3[q]; }
        float z4[3];
#pragma unroll
        for (int c = 0; c < 3; ++c) {
            float s = bagg[c];
#pragma unroll
            for (int q = 0; q < 15; ++q) s += cat[q] * Wagg[q*3 + c];
            z4[c] = s;
        }
        const float m = fmaxf(z4[0], fmaxf(z4[1], z4[2]));
        const float e0 = expf(z4[0]-m), e1 = expf(z4[1]-m), e2 = expf(z4[2]-m);
        const float inv = 1.f / (e0 + e1 + e2);
        bc[0] = e0*inv; bc[1] = e1*inv; bc[2] = e2*inv;
    }
    __syncthreads();
    if (t < 3) {
        nzT[t * NN + i]  = bc[t];
        nj_out[i*3 + t]  = bc[t];
    }
}

// ---------------- generic fp32 GEMM, BM=64 x BN=256(full), BK=16 ----------------
// AMODE: 0 = plain A
//        1 = A is on-the-fly blend of adj0/1/2 (WAB=1: also write blended A to AbOut)
//        2 = A-staging applies exp(a - Mrow[row]) and accumulates rowsum atomics
// ZMODE: 1 = blockIdx.y is k-split chunk (write partials, no bias)
//        2 = blockIdx.y selects batch {B0/B1/B2, C0/C1/C2, bias0/1/2} (full K, +bias)
template<int AMODE, int ZMODE, int WAB>
__global__ __launch_bounds__(256) void gemm256(
    const float* __restrict__ A0, const float* __restrict__ A1, const float* __restrict__ A2,
    const float* __restrict__ nzT,
    const float* __restrict__ B0, const float* __restrict__ B1, const float* __restrict__ B2,
    float* __restrict__ C0, float* __restrict__ C1, float* __restrict__ C2,
    const float* __restrict__ bias0, const float* __restrict__ bias1, const float* __restrict__ bias2,
    int M, int K, int lda, int kChunk,
    float* __restrict__ AbOut, const float* __restrict__ Mrow, float* __restrict__ rowsum)
{
    __shared__ float As[16][68];
    __shared__ float Bs[16][260];
    const int t  = threadIdx.x;
    const int tx = t & 15, ty = t >> 4;
    const int m0 = blockIdx.x * 64;
    const int bz = blockIdx.y;

    int kBegin = 0;
    const float* B = B0;
    const float* bias = nullptr;
    float* C = C0;
    if (ZMODE == 1) {
        kBegin = bz * kChunk;
        C = C0 + (size_t)bz * (size_t)M * NH;
    } else { // ZMODE == 2
        B    = (bz == 0) ? B0 : (bz == 1) ? B1 : B2;
        bias = (bz == 0) ? bias0 : (bz == 1) ? bias1 : bias2;
        C    = (bz == 0) ? C0 : (bz == 1) ? C1 : C2;
    }
    const int kEnd = kBegin + kChunk;

    float acc[4][16];
#pragma unroll
    for (int r = 0; r < 4; ++r)
#pragma unroll
        for (int c = 0; c < 16; ++c) acc[r][c] = 0.f;

    const int ar  = t >> 2, ac4 = t & 3;   // A staging: 64 rows x 1 float4
    const int bk0 = t >> 6, bc4 = t & 63;  // B staging: 4 passes of 4 k-rows x 64 float4

    float rowM = 0.f, expsum = 0.f;
    if (AMODE == 2) rowM = Mrow[m0 + ar];

    for (int kt = kBegin; kt < kEnd; kt += 16) {
        __syncthreads();
        {   // stage A (transposed, padded)
            const size_t aoff = (size_t)(m0 + ar) * lda + kt + ac4*4;
            float4 av;
            if (AMODE == 0) {
                av = ld4(A0 + aoff);
            } else if (AMODE == 1) {
                const float4 x0 = ld4(A0 + aoff);
                const float4 x1 = ld4(A1 + aoff);
                const float4 x2 = ld4(A2 + aoff);
                const int kc = kt + ac4*4;
                av = blend4(x0, x1, x2, ld4(nzT + kc), ld4(nzT + NN + kc), ld4(nzT + 2*NN + kc));
                if (WAB) st4(AbOut + aoff, av);
            } else { // AMODE == 2: exp(a - rowmax), accumulate row sum
                av = ld4(A0 + aoff);
                av.x = expf(av.x - rowM); av.y = expf(av.y - rowM);
                av.z = expf(av.z - rowM); av.w = expf(av.w - rowM);
                expsum += av.x + av.y + av.z + av.w;
            }
            As[ac4*4+0][ar] = av.x;
            As[ac4*4+1][ar] = av.y;
            As[ac4*4+2][ar] = av.z;
            As[ac4*4+3][ar] = av.w;
        }
#pragma unroll
        for (int q = 0; q < 4; ++q) {   // stage B
            const int kr = q*4 + bk0;
            st4(&Bs[kr][bc4*4], ld4(B + (size_t)(kt + kr)*NH + bc4*4));
        }
        __syncthreads();
#pragma unroll
        for (int kk = 0; kk < 16; ++kk) {
            const float4 a  = ld4(&As[kk][ty*4]);
            const float4 v0 = ld4(&Bs[kk][0*64 + tx*4]);
            const float4 v1 = ld4(&Bs[kk][1*64 + tx*4]);
            const float4 v2 = ld4(&Bs[kk][2*64 + tx*4]);
            const float4 v3 = ld4(&Bs[kk][3*64 + tx*4]);
            const float a4[4]  = {a.x, a.y, a.z, a.w};
            const float b16[16] = {v0.x,v0.y,v0.z,v0.w, v1.x,v1.y,v1.z,v1.w,
                                   v2.x,v2.y,v2.z,v2.w, v3.x,v3.y,v3.z,v3.w};
#pragma unroll
            for (int r = 0; r < 4; ++r)
#pragma unroll
                for (int c = 0; c < 16; ++c)
                    acc[r][c] += a4[r] * b16[c];
        }
    }
    if (AMODE == 2) {   // per-row partial sum of exp over this k-chunk
        expsum += __shfl_xor(expsum, 1, 64);
        expsum += __shfl_xor(expsum, 2, 64);
        if (ac4 == 0) atomicAdd(rowsum + m0 + ar, expsum);
    }
#pragma unroll
    for (int r = 0; r < 4; ++r) {
        const int m = m0 + ty*4 + r;
#pragma unroll
        for (int j = 0; j < 4; ++j) {
            const int c = j*64 + tx*4;
            float4 v = {acc[r][j*4+0], acc[r][j*4+1], acc[r][j*4+2], acc[r][j*4+3]};
            if (ZMODE == 2) {
                const float4 bb = ld4(bias + c);
                v.x += bb.x; v.y += bb.y; v.z += bb.z; v.w += bb.w;
            }
            st4(C + (size_t)m*NH + c, v);
        }
    }
}

// ---------------- reduce k-split partials (+bias, +relu, +row scale) ----------------
__global__ __launch_bounds__(256) void reduce_kernel(
    const float* __restrict__ parts, int S,
    const float* __restrict__ bias, int act,
    const float* __restrict__ rowsum, float* __restrict__ out)
{
    const int idx = blockIdx.x * 256 + threadIdx.x;   // float4 index, 393216 total
    float4 s = {0.f, 0.f, 0.f, 0.f};
    for (int z = 0; z < S; ++z) {
        const float4 v = ld4(parts + (size_t)z*6144*NH + (size_t)idx*4);
        s.x += v.x; s.y += v.y; s.z += v.z; s.w += v.w;
    }
    if (bias) {
        const float4 b = ld4(bias + (idx & 63)*4);
        s.x += b.x; s.y += b.y; s.z += b.z; s.w += b.w;
    }
    if (act) {
        s.x = fmaxf(s.x, 0.f); s.y = fmaxf(s.y, 0.f);
        s.z = fmaxf(s.z, 0.f); s.w = fmaxf(s.w, 0.f);
    }
    if (rowsum) {   // softmax normalization deferred past P@V (1/Z > 0 commutes with relu)
        const float inv = 1.f / rowsum[idx >> 6];
        s.x *= inv; s.y *= inv; s.z *= inv; s.w *= inv;
    }
    st4(out + (size_t)idx*4, s);
}

// ---------------- K6a: S = mask * (Q @ K^T), 128x128 tiles, + row-max partials ----
// USE_AB: 1 = mask is precomputed blended adjacency, 0 = blend on the fly
template<int USE_AB>
__global__ __launch_bounds__(256) void qk_mask_kernel(
    const float* __restrict__ Q, const float* __restrict__ Km,
    const float* __restrict__ Ab,
    const float* __restrict__ adj0, const float* __restrict__ adj1, const float* __restrict__ adj2,
    const float* __restrict__ nzT, float* __restrict__ Sout, float* __restrict__ Smax)
{
    __shared__ __align__(16) float Qs[16][132];
    __shared__ __align__(16) float Ks[16][132];
    const int t  = threadIdx.x;
    const int tx = t & 15, ty = t >> 4;
    const int m0 = blockIdx.x * 128;
    const int n0 = blockIdx.y * 128;
    const int ar = t >> 2, ac4 = t & 3;   // staging: rows ar and ar+64, col4 = ac4

    float acc[8][8];
#pragma unroll
    for (int r = 0; r < 8; ++r)
#pragma unroll
        for (int c = 0; c < 8; ++c) acc[r][c] = 0.f;

    for (int kt = 0; kt < NH; kt += 16) {
        __syncthreads();
        const float4 q0 = ld4(Q  + (size_t)(m0 + ar)      * NH + kt + ac4*4);
        const float4 q1 = ld4(Q  + (size_t)(m0 + ar + 64) * NH + kt + ac4*4);
        const float4 k0 = ld4(Km + (size_t)(n0 + ar)      * NH + kt + ac4*4);
        const float4 k1 = ld4(Km + (size_t)(n0 + ar + 64) * NH + kt + ac4*4);
        Qs[ac4*4+0][ar] = q0.x; Qs[ac4*4+1][ar] = q0.y;
        Qs[ac4*4+2][ar] = q0.z; Qs[ac4*4+3][ar] = q0.w;
        Qs[ac4*4+0][ar+64] = q1.x; Qs[ac4*4+1][ar+64] = q1.y;
        Qs[ac4*4+2][ar+64] = q1.z; Qs[ac4*4+3][ar+64] = q1.w;
        Ks[ac4*4+0][ar] = k0.x; Ks[ac4*4+1][ar] = k0.y;
        Ks[ac4*4+2][ar] = k0.z; Ks[ac4*4+3][ar] = k0.w;
        Ks[ac4*4+0][ar+64] = k1.x; Ks[ac4*4+1][ar+64] = k1.y;
        Ks[ac4*4+2][ar+64] = k1.z; Ks[ac4*4+3][ar+64] = k1.w;
        __syncthreads();
#pragma unroll
        for (int kk = 0; kk < 16; ++kk) {
            const float4 a0 = ld4(&Qs[kk][ty*4]);
            const float4 a1 = ld4(&Qs[kk][64 + ty*4]);
            const float4 b0 = ld4(&Ks[kk][tx*4]);
            const float4 b1 = ld4(&Ks[kk][64 + tx*4]);
            const float a8[8] = {a0.x,a0.y,a0.z,a0.w, a1.x,a1.y,a1.z,a1.w};
            const float b8[8] = {b0.x,b0.y,b0.z,b0.w, b1.x,b1.y,b1.z,b1.w};
#pragma unroll
            for (int r = 0; r < 8; ++r)
#pragma unroll
                for (int c = 0; c < 8; ++c)
                    acc[r][c] += a8[r] * b8[c];
        }
    }

    // mask-multiply, store S, emit per-(row, col-block) max partials
    float4 zc[2][3];
    if (!USE_AB) {
#pragma unroll
        for (int cf = 0; cf < 2; ++cf) {
            const int col = n0 + cf*64 + tx*4;
            zc[cf][0] = ld4(nzT + col);
            zc[cf][1] = ld4(nzT + NN + col);
            zc[cf][2] = ld4(nzT + 2*NN + col);
        }
    }
#pragma unroll
    for (int rf = 0; rf < 2; ++rf) {
#pragma unroll
        for (int r = 0; r < 4; ++r) {
            const int row = m0 + rf*64 + ty*4 + r;
            const int ri  = rf*4 + r;
            float rmax = -INFINITY;
#pragma unroll
            for (int cf = 0; cf < 2; ++cf) {
                const size_t off = (size_t)row * NN + n0 + cf*64 + tx*4;
                float4 mask;
                if (USE_AB) {
                    mask = ld4(Ab + off);
                } else {
                    mask = blend4(ld4(adj0+off), ld4(adj1+off), ld4(adj2+off),
                                  zc[cf][0], zc[cf][1], zc[cf][2]);
                }
                float4 v = {acc[ri][cf*4+0]*mask.x, acc[ri][cf*4+1]*mask.y,
                            acc[ri][cf*4+2]*mask.z, acc[ri][cf*4+3]*mask.w};
                st4(Sout + off, v);
                rmax = fmaxf(rmax, fmaxf(fmaxf(v.x, v.y), fmaxf(v.z, v.w)));
            }
#pragma unroll
            for (int d = 1; d < 16; d <<= 1) rmax = fmaxf(rmax, __shfl_xor(rmax, d, 64));
            if (tx == 0) Smax[(size_t)row * 48 + blockIdx.y] = rmax;
        }
    }
}

// ---------------- K6b': reduce row-max partials, zero rowsum ----------------
__global__ __launch_bounds__(256) void rowmax_kernel(
    const float* __restrict__ Smax, float* __restrict__ Mrow, float* __restrict__ rowsum)
{
    const int i = blockIdx.x * 256 + threadIdx.x;   // grid 24 -> 6144 rows
    float m = -INFINITY;
#pragma unroll
    for (int b = 0; b < 48; ++b) m = fmaxf(m, Smax[(size_t)i * 48 + b]);
    Mrow[i] = m;
    rowsum[i] = 0.f;
}

// ---------------- K7: xw2 = Xt @ W_g2  [6144,256]x[256,16] ----------------
__global__ __launch_bounds__(256) void xw2_kernel(
    const float* __restrict__ Xt, const float* __restrict__ Wg2, float* __restrict__ xw2)
{
    __shared__ float Xs[16*257];
    __shared__ float Ws[4096];
    const int t  = threadIdx.x;
    const int i0 = blockIdx.x * 16;
#pragma unroll
    for (int q = 0; q < 16; ++q) {
        Xs[q*257 + t] = Xt[(size_t)(i0 + q)*NH + t];
        Ws[q*256 + t] = Wg2[q*256 + t];
    }
    __syncthreads();
    const int r = t >> 4, c = t & 15;
    float acc = 0.f;
#pragma unroll 8
    for (int k = 0; k < 256; ++k)
        acc += Xs[r*257 + k] * Ws[k*16 + c];
    xw2[(size_t)(i0 + r)*16 + c] = acc;
}

// ---------------- K8: z = mask @ xw2 + b_g2 ; softmax16 -> out ----------------
template<int USE_AB>
__global__ __launch_bounds__(256) void final_kernel(
    const float* __restrict__ adj0, const float* __restrict__ adj1, const float* __restrict__ adj2,
    const float* __restrict__ Ab,
    const float* __restrict__ nzT, const float* __restrict__ xw2,
    const float* __restrict__ bg2, float* __restrict__ out)
{
    const int t  = threadIdx.x;
    const int i0 = blockIdx.x * 4;
    float acc[4][16];
#pragma unroll
    for (int r = 0; r < 4; ++r)
#pragma unroll
        for (int c = 0; c < 16; ++c) acc[r][c] = 0.f;

    for (int it = 0; it < 6; ++it) {
        const int j = (it*256 + t) * 4;
        float4 n0, n1, n2;
        if (!USE_AB) {
            n0 = ld4(nzT + j); n1 = ld4(nzT + NN + j); n2 = ld4(nzT + 2*NN + j);
        }
        float af[4][4];
#pragma unroll
        for (int r = 0; r < 4; ++r) {
            const size_t off = (size_t)(i0 + r)*NN + j;
            float4 a;
            if (USE_AB) a = ld4(Ab + off);
            else        a = blend4(ld4(adj0+off), ld4(adj1+off), ld4(adj2+off), n0, n1, n2);
            af[r][0] = a.x; af[r][1] = a.y; af[r][2] = a.z; af[r][3] = a.w;
        }
#pragma unroll
        for (int jj = 0; jj < 4; ++jj) {
            const float* w = xw2 + (size_t)(j + jj)*16;
            const float4 w0 = ld4(w), w1 = ld4(w+4), w2 = ld4(w+8), w3 = ld4(w+12);
            const float w16[16] = {w0.x,w0.y,w0.z,w0.w, w1.x,w1.y,w1.z,w1.w,
                                   w2.x,w2.y,w2.z,w2.w, w3.x,w3.y,w3.z,w3.w};
#pragma unroll
            for (int r = 0; r < 4; ++r) {
                const float a = af[r][jj];
#pragma unroll
                for (int c = 0; c < 16; ++c)
                    acc[r][c] += a * w16[c];
            }
        }
    }
#pragma unroll
    for (int r = 0; r < 4; ++r)
#pragma unroll
        for (int c = 0; c < 16; ++c) {
            float v = acc[r][c];
            for (int d = 1; d < 64; d <<= 1) v += __shfl_xor(v, d, 64);
            acc[r][c] = v;
        }
    __shared__ float red[4][4][16];
    const int wave = t >> 6;
    if ((t & 63) == 0) {
#pragma unroll
        for (int r = 0; r < 4; ++r)
#pragma unroll
            for (int c = 0; c < 16; ++c) red[wave][r][c] = acc[r][c];
    }
    __syncthreads();
    if (t < 64) {
        const int r = t >> 4, c = t & 15;
        const float z = red[0][r][c] + red[1][r][c] + red[2][r][c] + red[3][r][c] + bg2[c];
        float m = z;
        for (int d = 1; d < 16; d <<= 1) m = fmaxf(m, __shfl_xor(m, d, 16));
        const float e = expf(z - m);
        float s = e;
        for (int d = 1; d < 16; d <<= 1) s += __shfl_xor(s, d, 16);
        out[(size_t)(i0 + r)*16 + c] = e / s;
    }
}

extern "C" void kernel_launch(void* const* d_in, const int* in_sizes, int n_in,
                              void* d_out, int out_size, void* d_ws, size_t ws_size,
                              hipStream_t stream) {
    const float* adj0  = (const float*)d_in[0];
    const float* adj1  = (const float*)d_in[1];
    const float* adj2  = (const float*)d_in[2];
    const float* x     = (const float*)d_in[3];
    const float* W_at1 = (const float*)d_in[4];
    const float* b_at1 = (const float*)d_in[5];
    const float* W_at2 = (const float*)d_in[6];
    const float* b_at2 = (const float*)d_in[7];
    const float* W_at3 = (const float*)d_in[8];
    const float* b_at3 = (const float*)d_in[9];
    const float* W_agg = (const float*)d_in[10];
    const float* b_agg = (const float*)d_in[11];
    const float* W_g1  = (const float*)d_in[12];
    const float* b_g1  = (const float*)d_in[13];
    const float* W_g2  = (const float*)d_in[14];
    const float* b_g2  = (const float*)d_in[15];
    const float* W_q   = (const float*)d_in[16];
    const float* b_q   = (const float*)d_in[17];
    const float* W_k   = (const float*)d_in[18];
    const float* b_k   = (const float*)d_in[19];
    const float* W_v   = (const float*)d_in[20];
    const float* b_v   = (const float*)d_in[21];

    float* ws    = (float*)d_ws;
    float* Smat  = ws;                      // 37,748,736 floats
    float* parts = ws + 37748736;           // 8 x 1,572,864
    float* xw    = ws + 50331648;           // 1,572,864 (free after K4 -> reused below)
    float* h     = ws + 51904512;
    float* Qm    = ws + 53477376;
    float* Km    = ws + 55050240;
    float* Vm    = ws + 56623104;
    float* Xt    = ws + 58195968;
    float* xw2   = ws + 59768832;
    float* nzT   = ws + 59867136;           // 3 x 6144; base layout ends 59,885,568
    // reuse xw region (dead after K4) for softmax bookkeeping:
    float* Smax   = xw;                     // 6144 x 48
    float* Mrow   = xw + 294912;            // 6144
    float* rowsum = xw + 301056;            // 6144
    // blended adjacency (optional, needs 151 MB beyond base layout)
    float* Ab = ws + 59885568;              // 37,748,736 floats
    const bool use_ab = ws_size >= (size_t)(59885568 + 37748736) * sizeof(float);
    float* outF  = (float*)d_out;

    // K1: gating -> nzT, nj (out + 98304)
    gating_kernel<<<NN, 256, 0, stream>>>(adj0, adj1, adj2, W_at1, b_at1, W_at2, b_at2,
                                          W_at3, b_at3, W_agg, b_agg, nzT, outF + 98304);
    // K3: xw = x @ W_g1   (k-split 2)
    gemm256<0,1,0><<<dim3(96,2), 256, 0, stream>>>(x, nullptr, nullptr, nullptr,
        W_g1, nullptr, nullptr, parts, nullptr, nullptr, nullptr, nullptr, nullptr,
        NN, 512, 512, 256, nullptr, nullptr, nullptr);
    reduce_kernel<<<1536, 256, 0, stream>>>(parts, 2, nullptr, 0, nullptr, xw);
    // K4: h = relu(blend(adj) @ xw + b_g1)   (k-split 8); write Ab while staging if room
    if (use_ab)
        gemm256<1,1,1><<<dim3(96,8), 256, 0, stream>>>(adj0, adj1, adj2, nzT,
            xw, nullptr, nullptr, parts, nullptr, nullptr, nullptr, nullptr, nullptr,
            NN, NN, NN, 768, Ab, nullptr, nullptr);
    else
        gemm256<1,1,0><<<dim3(96,8), 256, 0, stream>>>(adj0, adj1, adj2, nzT,
            xw, nullptr, nullptr, parts, nullptr, nullptr, nullptr, nullptr, nullptr,
            NN, NN, NN, 768, nullptr, nullptr, nullptr);
    reduce_kernel<<<1536, 256, 0, stream>>>(parts, 8, b_g1, 1, nullptr, h);
    // K5: Q,K,V = h @ {W_q,W_k,W_v} + bias   (batched over blockIdx.y)
    gemm256<0,2,0><<<dim3(96,3), 256, 0, stream>>>(h, nullptr, nullptr, nullptr,
        W_q, W_k, W_v, Qm, Km, Vm, b_q, b_k, b_v, NN, 256, 256, 256,
        nullptr, nullptr, nullptr);
    // K6a: S = mask * (Q @ K^T), 128x128 tiles, emits row-max partials
    if (use_ab)
        qk_mask_kernel<1><<<dim3(48,48), 256, 0, stream>>>(Qm, Km, Ab,
            adj0, adj1, adj2, nzT, Smat, Smax);
    else
        qk_mask_kernel<0><<<dim3(48,48), 256, 0, stream>>>(Qm, Km, nullptr,
            adj0, adj1, adj2, nzT, Smat, Smax);
    // K6b': row maxima + zero rowsum (replaces full softmax passes)
    rowmax_kernel<<<24, 256, 0, stream>>>(Smax, Mrow, rowsum);
    // K6c: Xt_unnorm = exp(S - M) @ V  (k-split 8, exp fused into A staging,
    //      rowsum accumulated via atomics); reduce applies relu + 1/rowsum
    gemm256<2,1,0><<<dim3(96,8), 256, 0, stream>>>(Smat, nullptr, nullptr, nullptr,
        Vm, nullptr, nullptr, parts, nullptr, nullptr, nullptr, nullptr, nullptr,
        NN, NN, NN, 768, nullptr, Mrow, rowsum);
    reduce_kernel<<<1536, 256, 0, stream>>>(parts, 8, nullptr, 1, rowsum, Xt);
    // K7: xw2 = Xt @ W_g2
    xw2_kernel<<<384, 256, 0, stream>>>(Xt, W_g2, xw2);
    // K8: z = mask @ xw2 + b_g2 ; softmax -> out
    if (use_ab)
        final_kernel<1><<<1536, 256, 0, stream>>>(adj0, adj1, adj2, Ab, nzT, xw2, b_g2, outF);
    else
        final_kernel<0><<<1536, 256, 0, stream>>>(adj0, adj1, adj2, nullptr, nzT, xw2, b_g2, outF);
}